// Round 1
// baseline (216.180 us; speedup 1.0000x reference)
//
#include <hip/hip_runtime.h>
#include <math.h>

#define S_LEN 8192
#define HDIM  4096
#define H4    (HDIM / 4)      // 1024 float4 per row
#define P1_BLOCK 512
#define P1_WAVES (P1_BLOCK / 64)
#define FB_ATTN 8             // 8 blocks * 256 thr * 4 = 8192 attn elements

__device__ __forceinline__ float wave_reduce_sum(float x) {
#pragma unroll
  for (int o = 32; o > 0; o >>= 1) x += __shfl_xor(x, o, 64);
  return x;
}
__device__ __forceinline__ float wave_reduce_max(float x) {
#pragma unroll
  for (int o = 32; o > 0; o >>= 1) x = fmaxf(x, __shfl_xor(x, o, 64));
  return x;
}

// Single fused pass: energies (GEMV) + online softmax + weighted row accumulation.
// Each block owns `rpb` consecutive rows; per-thread accumulator covers 8 floats of H.
__global__ __launch_bounds__(P1_BLOCK) void pass1_k(
    const float* __restrict__ enc, const float* __restrict__ hidden,
    float* __restrict__ energies, float* __restrict__ mb, float* __restrict__ lb,
    float* __restrict__ opart, int rpb) {
  const int t = threadIdx.x;
  const int b = blockIdx.x;
  const int row0 = b * rpb;
  const int row1 = min(S_LEN, row0 + rpb);

  const float4* hv = (const float4*)hidden;
  const float4 h0 = hv[t];
  const float4 h1 = hv[t + P1_BLOCK];

  float4 a0 = {0.f, 0.f, 0.f, 0.f};
  float4 a1 = {0.f, 0.f, 0.f, 0.f};
  float m = -INFINITY, l = 0.f;

  __shared__ float red[P1_WAVES];
  const int wid = t >> 6;
  const bool lane0 = (t & 63) == 0;

  const float4* encv = (const float4*)enc;
  for (int r = row0; r < row1; ++r) {
    const float4* rp = encv + (size_t)r * H4;
    const float4 v0 = rp[t];
    const float4 v1 = rp[t + P1_BLOCK];
    float d = v0.x * h0.x + v0.y * h0.y + v0.z * h0.z + v0.w * h0.w
            + v1.x * h1.x + v1.y * h1.y + v1.z * h1.z + v1.w * h1.w;
    d = wave_reduce_sum(d);
    if (lane0) red[wid] = d;
    __syncthreads();
    float e = 0.f;
#pragma unroll
    for (int i = 0; i < P1_WAVES; ++i) e += red[i];
    __syncthreads();  // protect red[] before next row overwrites
    if (t == 0) energies[r] = e;

    const float mn = fmaxf(m, e);
    const float sc = __expf(m - mn);   // m=-inf first iter -> exp(-inf)=0, acc is 0 anyway
    const float w  = __expf(e - mn);
    l = l * sc + w;
    a0.x = fmaf(a0.x, sc, w * v0.x);
    a0.y = fmaf(a0.y, sc, w * v0.y);
    a0.z = fmaf(a0.z, sc, w * v0.z);
    a0.w = fmaf(a0.w, sc, w * v0.w);
    a1.x = fmaf(a1.x, sc, w * v1.x);
    a1.y = fmaf(a1.y, sc, w * v1.y);
    a1.z = fmaf(a1.z, sc, w * v1.z);
    a1.w = fmaf(a1.w, sc, w * v1.w);
    m = mn;
  }

  float4* op = (float4*)(opart + (size_t)b * HDIM);
  op[t] = a0;
  op[t + P1_BLOCK] = a1;
  if (t == 0) { mb[b] = m; lb[b] = l; }
}

// One block: global max over mb[0..Gu) and L = sum lb * exp(mb - m).
__global__ __launch_bounds__(1024) void stats_k(
    const float* __restrict__ mb, const float* __restrict__ lb,
    float* __restrict__ stats, int Gu) {
  const int t = threadIdx.x;
  __shared__ float red[16];
  float mv = (t < Gu) ? mb[t] : -INFINITY;
  float mw = wave_reduce_max(mv);
  if ((t & 63) == 0) red[t >> 6] = mw;
  __syncthreads();
  float gm = -INFINITY;
#pragma unroll
  for (int i = 0; i < 16; ++i) gm = fmaxf(gm, red[i]);
  __syncthreads();
  float li = (t < Gu) ? lb[t] * __expf(mb[t] - gm) : 0.f;
  float lw = wave_reduce_sum(li);
  if ((t & 63) == 0) red[t >> 6] = lw;
  __syncthreads();
  float L = 0.f;
#pragma unroll
  for (int i = 0; i < 16; ++i) L += red[i];
  if (t == 0) { stats[0] = gm; stats[1] = L; stats[2] = 1.f / L; }
}

// blocks [0,Bout): combine output partials over g-chunks via atomicAdd (out pre-zeroed).
// blocks [Bout, Bout+FB_ATTN): attn = exp(e - m)/L, vectorized float4.
__global__ __launch_bounds__(256) void finalize_k(
    const float* __restrict__ opart, const float* __restrict__ mb,
    const float* __restrict__ energies, const float* __restrict__ stats,
    float* __restrict__ out, int Gu, int Bout, int gpb) {
  const int t = threadIdx.x;
  const float gm  = stats[0];
  const float invL = stats[2];
  if ((int)blockIdx.x < Bout) {
    const int g0 = blockIdx.x * gpb;
    const int g1 = min(Gu, g0 + gpb);
    float4 acc[4] = {{0,0,0,0},{0,0,0,0},{0,0,0,0},{0,0,0,0}};
    for (int g = g0; g < g1; ++g) {
      const float w = __expf(mb[g] - gm) * invL;
      const float4* op = (const float4*)(opart + (size_t)g * HDIM);
#pragma unroll
      for (int k = 0; k < 4; ++k) {
        const float4 v = op[t + k * 256];
        acc[k].x += w * v.x; acc[k].y += w * v.y;
        acc[k].z += w * v.z; acc[k].w += w * v.w;
      }
    }
#pragma unroll
    for (int k = 0; k < 4; ++k) {
      const int h = (t + k * 256) * 4;
      atomicAdd(&out[h + 0], acc[k].x);
      atomicAdd(&out[h + 1], acc[k].y);
      atomicAdd(&out[h + 2], acc[k].z);
      atomicAdd(&out[h + 3], acc[k].w);
    }
  } else {
    const int i4 = ((int)blockIdx.x - Bout) * 256 + t;  // float4 index into [0,2048)
    const float4 e = ((const float4*)energies)[i4];
    float4 a;
    a.x = __expf(e.x - gm) * invL;
    a.y = __expf(e.y - gm) * invL;
    a.z = __expf(e.z - gm) * invL;
    a.w = __expf(e.w - gm) * invL;
    ((float4*)(out + HDIM))[i4] = a;
  }
}

extern "C" void kernel_launch(void* const* d_in, const int* in_sizes, int n_in,
                              void* d_out, int out_size, void* d_ws, size_t ws_size,
                              hipStream_t stream) {
  const float* hidden = (const float*)d_in[0];          // [4096] f32
  const float* enc    = (const float*)d_in[1];          // [8192,1,4096] f32
  float* out = (float*)d_out;                           // [4096 output | 8192 attn]
  float* wsf = (float*)d_ws;

  // workspace layout (floats):
  float* energies = wsf;            // 8192
  float* mb       = wsf + 8192;     // up to 1024
  float* lb       = wsf + 9216;     // up to 1024
  float* stats    = wsf + 10240;    // 16
  float* opart    = wsf + 10256;    // G * 4096

  const size_t avail_f = ws_size / 4;
  int Gmax = (avail_f > 10256) ? (int)((avail_f - 10256) / HDIM) : 1;
  int G = Gmax < 512 ? Gmax : 512;
  if (G < 1) G = 1;
  const int rpb = (S_LEN + G - 1) / G;
  const int Gu  = (S_LEN + rpb - 1) / rpb;   // blocks actually used, all non-empty

  hipMemsetAsync(d_out, 0, HDIM * sizeof(float), stream);  // atomics target
  pass1_k<<<Gu, P1_BLOCK, 0, stream>>>(enc, hidden, energies, mb, lb, opart, rpb);
  stats_k<<<1, 1024, 0, stream>>>(mb, lb, stats, Gu);

  int Bout = Gu < 128 ? Gu : 128;
  const int gpb = (Gu + Bout - 1) / Bout;
  Bout = (Gu + gpb - 1) / gpb;
  finalize_k<<<Bout + FB_ATTN, 256, 0, stream>>>(opart, mb, energies, stats, out, Gu, Bout, gpb);
}

// Round 2
// 210.915 us; speedup vs baseline: 1.0250x; 1.0250x over previous
//
#include <hip/hip_runtime.h>
#include <math.h>

#define S_LEN 8192
#define HDIM  4096
#define H4    (HDIM / 4)      // 1024 float4 per row
#define P1_BLOCK 512
#define P1_WAVES 8
#define RB 4                  // rows per barrier batch in pass1
#define FB_ATTN 8             // 8 blocks * 256 thr * 4 = 8192 attn elements

__device__ __forceinline__ float wave_reduce_sum(float x) {
#pragma unroll
  for (int o = 32; o > 0; o >>= 1) x += __shfl_xor(x, o, 64);
  return x;
}
__device__ __forceinline__ float wave_reduce_max(float x) {
#pragma unroll
  for (int o = 32; o > 0; o >>= 1) x = fmaxf(x, __shfl_xor(x, o, 64));
  return x;
}
__device__ __forceinline__ float dot4(float4 a, float4 b) {
  return a.x * b.x + a.y * b.y + a.z * b.z + a.w * b.w;
}
// acc = acc*sc + sum_r w[r]*x_r   (w[] statically indexed -> stays in regs)
__device__ __forceinline__ float upd(float a, float sc, const float* w,
                                     float x0, float x1, float x2, float x3) {
  float r = a * sc;
  r = fmaf(w[0], x0, r);
  r = fmaf(w[1], x1, r);
  r = fmaf(w[2], x2, r);
  r = fmaf(w[3], x3, r);
  return r;
}

// Fused GEMV + online softmax + weighted row accumulation.
// RB rows per barrier pair: 8 dwordx4 loads in flight per lane per drain.
__global__ __launch_bounds__(P1_BLOCK) void pass1_k(
    const float* __restrict__ enc, const float* __restrict__ hidden,
    float* __restrict__ energies, float* __restrict__ mb, float* __restrict__ lb,
    float* __restrict__ opart, int rpb) {
  const int t = threadIdx.x;
  const int b = blockIdx.x;
  const int row0 = b * rpb;
  const int row1 = min(S_LEN, row0 + rpb);

  const float4* hv = (const float4*)hidden;
  const float4 h0 = hv[t];
  const float4 h1 = hv[t + P1_BLOCK];

  float4 a0 = {0.f, 0.f, 0.f, 0.f};
  float4 a1 = {0.f, 0.f, 0.f, 0.f};
  float m = -INFINITY, l = 0.f;

  __shared__ float red[RB * P1_WAVES];
  const int wid = t >> 6;
  const bool lane0 = (t & 63) == 0;
  const float4* encv = (const float4*)enc;

  for (int r0 = row0; r0 < row1; r0 += RB) {
    const int nr = min(RB, row1 - r0);
    float4 v[RB][2];
    float d[RB];
#pragma unroll
    for (int r = 0; r < RB; ++r) {
      if (r < nr) {
        const float4* rp = encv + (size_t)(r0 + r) * H4;
        v[r][0] = rp[t];
        v[r][1] = rp[t + P1_BLOCK];
      } else {
        v[r][0] = make_float4(0.f, 0.f, 0.f, 0.f);
        v[r][1] = make_float4(0.f, 0.f, 0.f, 0.f);
      }
    }
#pragma unroll
    for (int r = 0; r < RB; ++r)
      d[r] = dot4(v[r][0], h0) + dot4(v[r][1], h1);
    // 4 independent wave reductions, interleaved shuffle chains
#pragma unroll
    for (int o = 32; o > 0; o >>= 1) {
#pragma unroll
      for (int r = 0; r < RB; ++r) d[r] += __shfl_xor(d[r], o, 64);
    }
    if (lane0) {
#pragma unroll
      for (int r = 0; r < RB; ++r) red[r * P1_WAVES + wid] = d[r];
    }
    __syncthreads();
    float e[RB];
#pragma unroll
    for (int r = 0; r < RB; ++r) {
      const float4 q0 = *(const float4*)&red[r * P1_WAVES];
      const float4 q1 = *(const float4*)&red[r * P1_WAVES + 4];
      e[r] = (q0.x + q0.y + q0.z + q0.w) + (q1.x + q1.y + q1.z + q1.w);
    }
    __syncthreads();  // protect red[] before next batch overwrites
    if (t == 0) {
      for (int r = 0; r < nr; ++r) energies[r0 + r] = e[r];
    }
    // batched online-softmax update: one rescale per RB rows
    float mn = m;
#pragma unroll
    for (int r = 0; r < RB; ++r)
      if (r < nr) mn = fmaxf(mn, e[r]);
    const float sc = __expf(m - mn);  // m=-inf first batch -> 0; acc/l are 0
    float w[RB];
#pragma unroll
    for (int r = 0; r < RB; ++r) w[r] = (r < nr) ? __expf(e[r] - mn) : 0.f;
    l = l * sc + w[0] + w[1] + w[2] + w[3];
    a0.x = upd(a0.x, sc, w, v[0][0].x, v[1][0].x, v[2][0].x, v[3][0].x);
    a0.y = upd(a0.y, sc, w, v[0][0].y, v[1][0].y, v[2][0].y, v[3][0].y);
    a0.z = upd(a0.z, sc, w, v[0][0].z, v[1][0].z, v[2][0].z, v[3][0].z);
    a0.w = upd(a0.w, sc, w, v[0][0].w, v[1][0].w, v[2][0].w, v[3][0].w);
    a1.x = upd(a1.x, sc, w, v[0][1].x, v[1][1].x, v[2][1].x, v[3][1].x);
    a1.y = upd(a1.y, sc, w, v[0][1].y, v[1][1].y, v[2][1].y, v[3][1].y);
    a1.z = upd(a1.z, sc, w, v[0][1].z, v[1][1].z, v[2][1].z, v[3][1].z);
    a1.w = upd(a1.w, sc, w, v[0][1].w, v[1][1].w, v[2][1].w, v[3][1].w);
    m = mn;
  }

  float4* op = (float4*)(opart + (size_t)b * HDIM);
  op[t] = a0;
  op[t + P1_BLOCK] = a1;
  if (t == 0) { mb[b] = m; lb[b] = l; }
}

// blocks [0,Bout): combine output partials over g-chunks via atomicAdd (out pre-zeroed).
// blocks [Bout, Bout+FB_ATTN): attn = exp(e - m)/L.
// Every block recomputes (gm, invL) locally from mb/lb (L2-hot, ~4 KB) — no stats kernel.
__global__ __launch_bounds__(256) void finalize_k(
    const float* __restrict__ opart, const float* __restrict__ mb,
    const float* __restrict__ lb, const float* __restrict__ energies,
    float* __restrict__ out, int Gu, int Bout, int gpb) {
  const int t = threadIdx.x;
  const int wid = t >> 6;
  const bool lane0 = (t & 63) == 0;
  __shared__ float smax[4], ssum[4];

  float mv = -INFINITY;
  for (int g = t; g < Gu; g += 256) mv = fmaxf(mv, mb[g]);
  mv = wave_reduce_max(mv);
  if (lane0) smax[wid] = mv;
  __syncthreads();
  const float gm = fmaxf(fmaxf(smax[0], smax[1]), fmaxf(smax[2], smax[3]));

  float lv = 0.f;
  for (int g = t; g < Gu; g += 256) lv += lb[g] * __expf(mb[g] - gm);
  lv = wave_reduce_sum(lv);
  if (lane0) ssum[wid] = lv;
  __syncthreads();
  const float invL = 1.f / (ssum[0] + ssum[1] + ssum[2] + ssum[3]);

  if ((int)blockIdx.x < Bout) {
    const int g0 = blockIdx.x * gpb;
    const int g1 = min(Gu, g0 + gpb);
    float4 acc[4] = {{0,0,0,0},{0,0,0,0},{0,0,0,0},{0,0,0,0}};
    for (int g = g0; g < g1; ++g) {
      const float w = __expf(mb[g] - gm) * invL;
      const float4* op = (const float4*)(opart + (size_t)g * HDIM);
#pragma unroll
      for (int k = 0; k < 4; ++k) {
        const float4 v = op[t + k * 256];
        acc[k].x = fmaf(w, v.x, acc[k].x);
        acc[k].y = fmaf(w, v.y, acc[k].y);
        acc[k].z = fmaf(w, v.z, acc[k].z);
        acc[k].w = fmaf(w, v.w, acc[k].w);
      }
    }
#pragma unroll
    for (int k = 0; k < 4; ++k) {
      const int h = (t + k * 256) * 4;
      atomicAdd(&out[h + 0], acc[k].x);
      atomicAdd(&out[h + 1], acc[k].y);
      atomicAdd(&out[h + 2], acc[k].z);
      atomicAdd(&out[h + 3], acc[k].w);
    }
  } else {
    const int i4 = ((int)blockIdx.x - Bout) * 256 + t;  // float4 idx into [0,2048)
    const float4 e = ((const float4*)energies)[i4];
    float4 a;
    a.x = __expf(e.x - gm) * invL;
    a.y = __expf(e.y - gm) * invL;
    a.z = __expf(e.z - gm) * invL;
    a.w = __expf(e.w - gm) * invL;
    ((float4*)(out + HDIM))[i4] = a;
  }
}

extern "C" void kernel_launch(void* const* d_in, const int* in_sizes, int n_in,
                              void* d_out, int out_size, void* d_ws, size_t ws_size,
                              hipStream_t stream) {
  const float* hidden = (const float*)d_in[0];          // [4096] f32
  const float* enc    = (const float*)d_in[1];          // [8192,1,4096] f32
  float* out = (float*)d_out;                           // [4096 output | 8192 attn]
  float* wsf = (float*)d_ws;

  // workspace layout (floats):
  float* energies = wsf;            // 8192
  float* mb       = wsf + 8192;     // up to 1024
  float* lb       = wsf + 9216;     // up to 1024
  float* opart    = wsf + 10240;    // G * 4096

  const size_t avail_f = ws_size / 4;
  int Gmax = (avail_f > 10240) ? (int)((avail_f - 10240) / HDIM) : 1;
  int G = Gmax < 512 ? Gmax : 512;
  if (G < 1) G = 1;
  const int rpb = (S_LEN + G - 1) / G;
  const int Gu  = (S_LEN + rpb - 1) / rpb;   // blocks actually used, all non-empty

  hipMemsetAsync(d_out, 0, HDIM * sizeof(float), stream);  // atomics target
  pass1_k<<<Gu, P1_BLOCK, 0, stream>>>(enc, hidden, energies, mb, lb, opart, rpb);

  int Bout = Gu < 128 ? Gu : 128;
  const int gpb = (Gu + Bout - 1) / Bout;
  Bout = (Gu + gpb - 1) / gpb;
  finalize_k<<<Bout + FB_ATTN, 256, 0, stream>>>(opart, mb, lb, energies, out, Gu, Bout, gpb);
}